// Round 6
// baseline (1205.111 us; speedup 1.0000x reference)
//
#include <hip/hip_runtime.h>
#include <hip/hip_bf16.h>

#define Bq 64
#define Lq 256
#define Dq 350
#define HDq 128
#define Hq 256
#define G4 512   // 4*HD

typedef unsigned short u16;
typedef unsigned int u32;
typedef __attribute__((ext_vector_type(8))) short bf16x8;
typedef __attribute__((ext_vector_type(4))) float f32x4;

__device__ __forceinline__ float bf2f(u16 u) {
    return __uint_as_float(((u32)u) << 16);
}
__device__ __forceinline__ u16 f2bf(float f) {
    __hip_bfloat16 h = __float2bfloat16(f);
    return *(u16*)&h;
}
__device__ __forceinline__ float bflo(u32 u) {
    return __uint_as_float(u << 16);
}
__device__ __forceinline__ float bfhi(u32 u) {
    return __uint_as_float(u & 0xffff0000u);
}
__device__ __forceinline__ float loadf(const void* p, long i, int f32) {
    return f32 ? ((const float*)p)[i] : bf2f(((const u16*)p)[i]);
}
// extract bf16 element i (0..7) from a uint4 (compile-time i folds to regs)
__device__ __forceinline__ float pick8(uint4 q, int i) {
    u32 w = (i >> 1) == 0 ? q.x : (i >> 1) == 1 ? q.y : (i >> 1) == 2 ? q.z : q.w;
    return (i & 1) ? bfhi(w) : bflo(w);
}
__device__ __forceinline__ float sigm(float x) {
    x = fminf(fmaxf(x, -30.f), 30.f);
    return 1.f / (1.f + __expf(-x));
}
__device__ __forceinline__ float tanh_(float x) {
    x = fminf(fmaxf(x, -15.f), 15.f);
    float e = __expf(2.f * x);
    return (e - 1.f) / (e + 1.f);
}
// fast, clamp-free (graceful at +/-inf) for the LSTM hot loop
__device__ __forceinline__ float fsigm(float x) {
    return 1.f / (1.f + __expf(-x));
}
__device__ __forceinline__ float ftanh(float x) {
    return 1.f - 2.f / (__expf(2.f * x) + 1.f);
}
__device__ __forceinline__ float lse2(float x, float y) {
    float m = fmaxf(x, y);
    return m + logf(expf(x - m) + expf(y - m));
}

// ---------------------------------------------------------------------------
// Kernel 0: dtype detector (proven R4/R5). flag=1 => float inputs are f32.
// ---------------------------------------------------------------------------
__global__ void detect_kernel(const void* we, int* flag) {
    if (threadIdx.x == 0 && blockIdx.x == 0) {
        const u16* p = (const u16*)we;
        int big = 0;
        for (int i = 0; i < 256; ++i) {
            float a = fabsf(bf2f(p[i]));
            if (!(a < 2.f)) big++;   // counts NaN too
        }
        *flag = (big > 16) ? 1 : 0;
    }
}

// ---------------------------------------------------------------------------
// Kernel 1: fused embedding-gather + input GEMM. Writes xs in the LSTM's
// MFMA C-fragment order, 8-step chunked:
//   xsF[row][tc][lane][r][u]  (bf16)
//   row = ((dir*4+bg)*8 + w)*4 + g   (bg=b>>4, w=(n&127)>>4, g=n>>7)
//   lane = (m>>2)*16 + (n&15), r = m&3, m = b&15, tc = s>>3, u = s&7
//   s = step index (dir1: s = len-1-pos).
// ---------------------------------------------------------------------------
#define BM 64
#define BN 64
#define BK 32
#define LDT 68  // padded LDS row stride (floats)

__global__ __launch_bounds__(256) void gemm_xs_kernel(
    const int* __restrict__ sents, const int* __restrict__ masks,
    const int* __restrict__ lens,
    const void* __restrict__ word_embed,
    const void* __restrict__ mask_embed,
    const void* __restrict__ w_ih_f, const void* __restrict__ w_ih_b,
    const void* __restrict__ b_ih_f, const void* __restrict__ b_hh_f,
    const void* __restrict__ b_ih_b, const void* __restrict__ b_hh_b,
    const int* __restrict__ flag,
    u16* __restrict__ xsF)
{
    __shared__ __align__(16) float As[BK * LDT];
    __shared__ __align__(16) float Bs[BK * LDT];
    __shared__ int rowS[BM];
    __shared__ int rowM[BM];

    int f32 = *flag;
    int tid = threadIdx.x;
    int mBase = blockIdx.y * BM;
    int jGlob = blockIdx.x * BN;   // [0, 1024)
    int dir = jGlob >> 9;
    int jj = jGlob & 511;
    const void* w_ih = dir ? w_ih_b : w_ih_f;
    const void* b_ih = dir ? b_ih_b : b_ih_f;
    const void* b_hh = dir ? b_hh_b : b_hh_f;

    int b = mBase >> 8;
    int posBase = mBase & 255;
    int len = lens[b];

    if (tid < BM) {
        int i = mBase + tid;
        rowS[tid] = sents[i] * 300;
        rowM[tid] = masks[i] * 50;
    }
    int ty = tid >> 4, tx = tid & 15;
    float acc[4][4] = {};
    __syncthreads();

    for (int kt = 0; kt < 11; ++kt) {
        int k0 = kt * BK;
#pragma unroll
        for (int e = 0; e < 8; ++e) {
            int idx = e * 256 + tid;
            int m = idx >> 5, kk = idx & 31;
            int gk = k0 + kk;
            float av = 0.f;
            if (gk < 300)      av = loadf(word_embed, rowS[m] + gk, f32);
            else if (gk < 350) av = loadf(mask_embed, rowM[m] + gk - 300, f32);
            As[kk * LDT + m] = av;
            float bv = 0.f;
            if (gk < 350) bv = loadf(w_ih, (long)(jj + m) * 350 + gk, f32);
            Bs[kk * LDT + m] = bv;
        }
        __syncthreads();
#pragma unroll
        for (int kk = 0; kk < BK; ++kk) {
            float4 a4 = *(const float4*)&As[kk * LDT + ty * 4];
            float4 b4 = *(const float4*)&Bs[kk * LDT + tx * 4];
            float a[4] = {a4.x, a4.y, a4.z, a4.w};
            float bb[4] = {b4.x, b4.y, b4.z, b4.w};
#pragma unroll
            for (int r = 0; r < 4; ++r)
#pragma unroll
                for (int c = 0; c < 4; ++c)
                    acc[r][c] = fmaf(a[r], bb[c], acc[r][c]);
        }
        __syncthreads();
    }

    int dim = jj + tx * 4;
    float bias[4];
#pragma unroll
    for (int c = 0; c < 4; ++c)
        bias[c] = loadf(b_ih, dim + c, f32) + loadf(b_hh, dim + c, f32);

    int bgv = b >> 4, mm = b & 15;
    int quadv = mm >> 2, rr = mm & 3;
#pragma unroll
    for (int r = 0; r < 4; ++r) {
        int pos = posBase + ty * 4 + r;
        int s = dir ? (len - 1 - pos) : pos;
        if (s >= 0) {
#pragma unroll
            for (int c = 0; c < 4; ++c) {
                int n = dim + c;
                int g = n >> 7, dd = n & 127;
                int wv = dd >> 4, colv = dd & 15;
                int lanev = quadv * 16 + colv;
                int rowg = ((dir * 4 + bgv) * 8 + wv) * 4 + g;
                long idxe = ((long)(rowg * 32 + (s >> 3)) * 64 + lanev) * 32
                            + rr * 8 + (s & 7);
                xsF[idxe] = f2bf(acc[r][c] + bias[c]);
            }
        }
    }
}

// ---------------------------------------------------------------------------
// Kernel 2: MFMA LSTM. 8 blocks (4 bgroups x 2 dirs) x 512 threads (8 waves).
// Per step: gates[16b][512n] = H[16][128] x W^T via 16x16x32 bf16 MFMA.
// Wave w owns n = {g*128 + 16w .. +16} for g=0..3 => i,f,g,o for a (b,d)
// land in the same lane (C layout col=lane&15=n, row=quad*4+reg=m=batch).
// Cell state in VGPRs; h via padded LDS; history flushed every 16 steps.
// ---------------------------------------------------------------------------
__global__ __launch_bounds__(512, 1) void lstm_mfma_kernel(
    const u16* __restrict__ xsF,
    const void* __restrict__ w_hh_f, const void* __restrict__ w_hh_b,
    const int* __restrict__ lens, const int* __restrict__ flag,
    u16* __restrict__ context)
{
    int f32 = *flag;
    int blk = blockIdx.x;
    int dir = blk >> 2, bg = blk & 3;
    int tid = threadIdx.x;
    int w = tid >> 6, lane = tid & 63;
    int quad = lane >> 4, col = lane & 15;
    const void* w_hh = dir ? w_hh_b : w_hh_f;

    __shared__ __align__(16) u16 h_lds[16 * 136];   // [m][d], pad 136
    __shared__ __align__(16) u16 hist[16 * 2048];   // [t&15][m*128+d], 64KB
    __shared__ int len_s[16];
    __shared__ int maxlen_s;

    if (tid < 16) len_s[tid] = lens[bg * 16 + tid];
    for (int i = tid; i < 16 * 136; i += 512) h_lds[i] = 0;
    __syncthreads();
    if (tid == 0) {
        int mx = 0;
        for (int m = 0; m < 16; ++m) mx = max(mx, len_s[m]);
        maxlen_s = mx;
    }
    // zero-fill context for invalid pos (this dir's half)
    for (int m = 0; m < 16; ++m) {
        int b = bg * 16 + m;
        int len = len_s[m];
        for (int idx = tid; idx < (Lq - len) * HDq; idx += 512) {
            int p = len + (idx >> 7);
            int d = idx & 127;
            context[((b << 8) + p) * Hq + dir * HDq + d] = 0;
        }
    }
    __syncthreads();
    int T16 = (maxlen_s + 15) & ~15;

    // B-fragments: wfrag[g][c] holds W[n][k], n = g*128+16w+col, k = 32c+8*quad+j
    bf16x8 wfrag[4][4];
#pragma unroll
    for (int g = 0; g < 4; ++g) {
        int n = g * 128 + w * 16 + col;
#pragma unroll
        for (int c = 0; c < 4; ++c) {
            int k0 = c * 32 + quad * 8;
            bf16x8 fr;
            if (f32) {
                const float* src = (const float*)w_hh + (long)n * 128 + k0;
#pragma unroll
                for (int j = 0; j < 8; ++j) fr[j] = (short)f2bf(src[j]);
            } else {
                fr = *(const bf16x8*)((const u16*)w_hh + (long)n * 128 + k0);
            }
            wfrag[g][c] = fr;
        }
    }

    float c_st[4] = {0.f, 0.f, 0.f, 0.f};
    int lenr[4];
#pragma unroll
    for (int r = 0; r < 4; ++r) lenr[r] = len_s[quad * 4 + r];

    int nCh = T16 >> 3;
    for (int tc = 0; tc < nCh; ++tc) {
        // stream 8 steps of xs in C-frag order (16 coalesced b128 loads)
        uint4 xsr[4][4];
#pragma unroll
        for (int g = 0; g < 4; ++g) {
            int rowg = ((dir * 4 + bg) * 8 + w) * 4 + g;
            const uint4* p4 = (const uint4*)(xsF +
                ((long)(rowg * 32 + tc) * 64 + lane) * 32);
#pragma unroll
            for (int r = 0; r < 4; ++r) xsr[g][r] = p4[r];
        }
#pragma unroll
        for (int u = 0; u < 8; ++u) {
            int t = tc * 8 + u;
            __syncthreads();   // h_lds from previous step visible
            bf16x8 af[4];
#pragma unroll
            for (int c = 0; c < 4; ++c)
                af[c] = *(const bf16x8*)&h_lds[col * 136 + c * 32 + quad * 8];
            f32x4 acc[4];
#pragma unroll
            for (int g = 0; g < 4; ++g) {
                f32x4 a4;
                a4[0] = pick8(xsr[g][0], u);
                a4[1] = pick8(xsr[g][1], u);
                a4[2] = pick8(xsr[g][2], u);
                a4[3] = pick8(xsr[g][3], u);
                acc[g] = a4;
            }
#pragma unroll
            for (int c = 0; c < 4; ++c)
#pragma unroll
                for (int g = 0; g < 4; ++g)
                    acc[g] = __builtin_amdgcn_mfma_f32_16x16x32_bf16(
                        af[c], wfrag[g][c], acc[g], 0, 0, 0);
            u16 hnew[4];
            bool vld[4];
#pragma unroll
            for (int r = 0; r < 4; ++r) {
                vld[r] = (t < lenr[r]);
                float i_ = fsigm(acc[0][r]);
                float f_ = fsigm(acc[1][r]);
                float g_ = ftanh(acc[2][r]);
                float o_ = fsigm(acc[3][r]);
                float cn = f_ * c_st[r] + i_ * g_;
                if (vld[r]) c_st[r] = cn;
                hnew[r] = f2bf(o_ * ftanh(cn));
            }
            __syncthreads();   // all A-frag reads done before h_lds update
#pragma unroll
            for (int r = 0; r < 4; ++r) {
                if (vld[r]) {
                    int m = quad * 4 + r, d = w * 16 + col;
                    h_lds[m * 136 + d] = hnew[r];
                    hist[(t & 15) * 2048 + m * 128 + d] = hnew[r];
                }
            }
            if ((t & 15) == 15) {
                __syncthreads();   // hist complete
                int tb = t - 15;
                for (int idx = tid; idx < 16384; idx += 512) {
                    int tl = idx >> 10;
                    int rem = idx & 1023;
                    int m = rem >> 6;
                    int d2 = (rem & 63) << 1;
                    int tt = tb + tl;
                    int len = len_s[m];
                    if (tt < len) {
                        int pos = dir ? (len - 1 - tt) : tt;
                        int b = bg * 16 + m;
                        u32 v = *(const u32*)&hist[tl * 2048 + m * 128 + d2];
                        *(u32*)&context[((b << 8) + pos) * Hq + dir * HDq + d2] = v;
                    }
                }
            }
        }
    }
}

// ---------------------------------------------------------------------------
// Kernel 3: tavg (unchanged)
// ---------------------------------------------------------------------------
__global__ void tavg_kernel(const int* __restrict__ masks,
                            const u16* __restrict__ context,
                            float* __restrict__ tavg)
{
    int b = blockIdx.x, h = threadIdx.x;
    float s = 0.f, msum = 0.f;
    for (int l = 0; l < Lq; ++l) {
        int m = masks[(b << 8) + l];
        if (m) {
            s += (float)m * bf2f(context[(((b << 8) + l) << 8) + h]);
            msum += (float)m;
        }
    }
    tavg[(b << 8) + h] = s / msum;
}

// ---------------------------------------------------------------------------
// Kernel 4: emit (unchanged)
// ---------------------------------------------------------------------------
__global__ void emit_kernel(const u16* __restrict__ context,
                            const float* __restrict__ tavg,
                            const void* __restrict__ f2t_w,
                            const void* __restrict__ f2t_b,
                            const int* __restrict__ flag,
                            float* __restrict__ emit)
{
    int f32 = *flag;
    int i = blockIdx.x;
    int b = i >> 8;
    int k = threadIdx.x;  // 0..63
    ushort4 c4 = *(const ushort4*)(context + (long)i * Hq + 4 * k);
    float4 t4 = *(const float4*)(tavg + b * Hq + 4 * k);
    float v0 = bf2f(c4.x) + t4.x, v1 = bf2f(c4.y) + t4.y;
    float v2 = bf2f(c4.z) + t4.z, v3 = bf2f(c4.w) + t4.w;
    int d = 4 * k;
    float p0 = v0 * loadf(f2t_w, d, f32) + v1 * loadf(f2t_w, d + 1, f32) +
               v2 * loadf(f2t_w, d + 2, f32) + v3 * loadf(f2t_w, d + 3, f32);
    float p1 = v0 * loadf(f2t_w, Hq + d, f32) + v1 * loadf(f2t_w, Hq + d + 1, f32) +
               v2 * loadf(f2t_w, Hq + d + 2, f32) + v3 * loadf(f2t_w, Hq + d + 3, f32);
#pragma unroll
    for (int off = 32; off >= 1; off >>= 1) {
        p0 += __shfl_down(p0, off);
        p1 += __shfl_down(p1, off);
    }
    if (k == 0) {
        emit[i * 2 + 0] = p0 + loadf(f2t_b, 0, f32);
        emit[i * 2 + 1] = p1 + loadf(f2t_b, 1, f32);
    }
}

// ---------------------------------------------------------------------------
// Kernel 5: CRF forward-backward (unchanged)
// ---------------------------------------------------------------------------
__global__ void crf_kernel(const float* __restrict__ emit,
                           const int* __restrict__ lens,
                           const void* __restrict__ trans,
                           const int* __restrict__ flag,
                           float* __restrict__ alphas, float* __restrict__ sp,
                           float* __restrict__ spsum)
{
    int f32 = *flag;
    int b = threadIdx.x;
    float t00 = loadf(trans, 0, f32), t01 = loadf(trans, 1, f32);
    float t10 = loadf(trans, 2, f32), t11 = loadf(trans, 3, f32);
    int len = lens[b];
    const float* eb = emit + ((long)(b << 8)) * 2;
    float* ab = alphas + ((long)(b << 8)) * 2;

    float a0 = eb[0], a1 = eb[1];
    ab[0] = a0; ab[1] = a1;
    for (int t = 1; t < Lq; ++t) {
        if (t < len) {
            float e0 = eb[2 * t], e1 = eb[2 * t + 1];
            float n0 = e0 + lse2(a0 + t00, a1 + t10);
            float n1 = e1 + lse2(a0 + t01, a1 + t11);
            a0 = n0; a1 = n1;
        }
        ab[2 * t] = a0; ab[2 * t + 1] = a1;
    }
    float logZ = lse2(a0, a1);

    float b0 = 0.f, b1 = 0.f;
    float ssum = 0.f;
    {
        float v = (Lq - 1 < len) ? expf(ab[2 * (Lq - 1) + 1] - logZ) : 0.f;
        sp[(b << 8) + Lq - 1] = v; ssum += v;
    }
    for (int t = Lq - 1; t >= 1; --t) {
        if (t < len) {
            float e0 = eb[2 * t], e1 = eb[2 * t + 1];
            float n0 = lse2(t00 + e0 + b0, t01 + e1 + b1);
            float n1 = lse2(t10 + e0 + b0, t11 + e1 + b1);
            b0 = n0; b1 = n1;
        }
        float v = ((t - 1) < len) ? expf(ab[2 * (t - 1) + 1] + b1 - logZ) : 0.f;
        sp[(b << 8) + t - 1] = v; ssum += v;
    }
    spsum[b] = ssum;
}

// ---------------------------------------------------------------------------
// Kernel 6: sentv (unchanged)
// ---------------------------------------------------------------------------
__global__ void sentv_kernel(const float* __restrict__ sp,
                             const u16* __restrict__ context,
                             const float* __restrict__ tavg,
                             const float* __restrict__ spsum,
                             float* __restrict__ sentv)
{
    int b = blockIdx.x, h = threadIdx.x;
    float s = 0.f;
    for (int l = 0; l < Lq; ++l)
        s += sp[(b << 8) + l] * bf2f(context[(((b << 8) + l) << 8) + h]);
    sentv[(b << 8) + h] = s + spsum[b] * tavg[(b << 8) + h];
}

// ---------------------------------------------------------------------------
// Kernel 7: final loss (unchanged)
// ---------------------------------------------------------------------------
__global__ void final_kernel(const float* __restrict__ sentv,
                             const float* __restrict__ spsum,
                             const void* __restrict__ f2l_w,
                             const void* __restrict__ f2l_b,
                             const void* __restrict__ trans,
                             const int* __restrict__ labels,
                             const int* __restrict__ flag,
                             void* __restrict__ out)
{
    int f32 = *flag;
    int b = threadIdx.x;  // 64 lanes
    float s0 = 0.f, s1 = 0.f, s2 = 0.f;
    for (int h = 0; h < Hq; ++h) {
        float v = sentv[(b << 8) + h];
        s0 += v * loadf(f2l_w, h, f32);
        s1 += v * loadf(f2l_w, Hq + h, f32);
        s2 += v * loadf(f2l_w, 2 * Hq + h, f32);
    }
    s0 += loadf(f2l_b, 0, f32); s1 += loadf(f2l_b, 1, f32); s2 += loadf(f2l_b, 2, f32);
    float m = fmaxf(s0, fmaxf(s1, s2));
    float lse = m + logf(expf(s0 - m) + expf(s1 - m) + expf(s2 - m));
    int lab = labels[b];
    float sc = lab == 0 ? s0 : (lab == 1 ? s1 : s2);
    float loss = lse - sc;
    float sn = spsum[b];
#pragma unroll
    for (int off = 32; off >= 1; off >>= 1) {
        loss += __shfl_down(loss, off);
        sn += __shfl_down(sn, off);
    }
    if (b == 0) {
        float cls = loss / 64.f;
        float t00 = loadf(trans, 0, f32), t01 = loadf(trans, 1, f32);
        float t10 = loadf(trans, 2, f32), t11 = loadf(trans, 3, f32);
        float pena = fmaxf(t10 - t00, 0.f) + fmaxf(t01 - t11, 0.f);
        float np = 1.0f * pena + 0.1f * (sn / 64.f);
        if (f32) {
            ((float*)out)[0] = cls;
            ((float*)out)[1] = np;
        } else {
            ((__hip_bfloat16*)out)[0] = __float2bfloat16(cls);
            ((__hip_bfloat16*)out)[1] = __float2bfloat16(np);
        }
    }
}

extern "C" void kernel_launch(void* const* d_in, const int* in_sizes, int n_in,
                              void* d_out, int out_size, void* d_ws, size_t ws_size,
                              hipStream_t stream)
{
    const int* sents  = (const int*)d_in[0];
    const int* masks  = (const int*)d_in[1];
    const int* labels = (const int*)d_in[2];
    const int* lens   = (const int*)d_in[3];
    const void* word_embed = d_in[4];
    const void* mask_embed = d_in[5];
    const void* w_ih_f = d_in[6];
    const void* w_hh_f = d_in[7];
    const void* b_ih_f = d_in[8];
    const void* b_hh_f = d_in[9];
    const void* w_ih_b = d_in[10];
    const void* w_hh_b = d_in[11];
    const void* b_ih_b = d_in[12];
    const void* b_hh_b = d_in[13];
    const void* f2t_w  = d_in[14];
    const void* f2t_b  = d_in[15];
    const void* trans  = d_in[16];
    const void* f2l_w  = d_in[17];
    const void* f2l_b  = d_in[18];

    // workspace layout: identical byte budget to R5's proven 42.4 MB
    char* wsb = (char*)d_ws;
    size_t off = 33554432;                   // xsF: 256*32*64*32 bf16 = 32 MB
    u16*   xsF     = (u16*)wsb;
    u16*   context = (u16*)(wsb + off);      off += 8388608;
    float* tavg    = (float*)(wsb + off);    off += 65536;
    float* alphas  = (float*)(wsb + off);    off += 131072;
    float* emit    = (float*)(wsb + off);    off += 131072;
    float* sp      = (float*)(wsb + off);    off += 65536;
    float* spsum   = (float*)(wsb + off);    off += 4096;
    float* sentv   = (float*)(wsb + off);    off += 65536;
    int*   flag    = (int*)(wsb + off);

    detect_kernel<<<1, 64, 0, stream>>>(word_embed, flag);

    gemm_xs_kernel<<<dim3(16, 256), 256, 0, stream>>>(
        sents, masks, lens, word_embed, mask_embed,
        w_ih_f, w_ih_b, b_ih_f, b_hh_f, b_ih_b, b_hh_b, flag, xsF);

    lstm_mfma_kernel<<<8, 512, 0, stream>>>(
        xsF, w_hh_f, w_hh_b, lens, flag, context);

    tavg_kernel<<<Bq, 256, 0, stream>>>(masks, context, tavg);

    emit_kernel<<<Bq * Lq, 64, 0, stream>>>(context, tavg, f2t_w, f2t_b, flag, emit);

    crf_kernel<<<1, 64, 0, stream>>>(emit, lens, trans, flag, alphas, sp, spsum);

    sentv_kernel<<<Bq, 256, 0, stream>>>(sp, context, tavg, spsum, sentv);

    final_kernel<<<1, 64, 0, stream>>>(sentv, spsum, f2l_w, f2l_b, trans, labels,
                                       flag, d_out);
}